// Round 17
// baseline (296.507 us; speedup 1.0000x reference)
//
#include <hip/hip_runtime.h>
#include <hip/hip_bf16.h>
#include <stdint.h>

// B=4, S=4096, DIMS=1024, HEAD=16, HD=64, skip=4 (S_k=1024)
// cvtall -> proj_fused (256x128-tile 4-phase counted-vmcnt GEMM: Q | fused K/V) ->
// flash attn (unchanged control) -> oproj (same template)
// ROUND 17 FIX: KV sub-launch grid was 64 blocks; needs 16 Mblk x 16 Nblk = 256
// (M = B*S_k = 4096 rows, not 1024). proj_fused grid 576 -> 768.

using short8 = short __attribute__((ext_vector_type(8)));
using f32x4  = float __attribute__((ext_vector_type(4)));
using f32x16 = float __attribute__((ext_vector_type(16)));

#define MFMA16(A,B,C) __builtin_amdgcn_mfma_f32_16x16x32_bf16((A),(B),(C),0,0,0)
#define MFMA32(A,B,C) __builtin_amdgcn_mfma_f32_32x32x16_bf16((A),(B),(C),0,0,0)

#define QSC 0.0450842200277800f      // scale * log2(e), folded into Q-proj epilogue
#define VT_OFF 4194304               // V^T offset (ushorts) from K buffer

__device__ __forceinline__ unsigned short f2bf(float f) {
  unsigned int x = __float_as_uint(f);
  x += 0x7fffu + ((x >> 16) & 1u);   // RNE
  return (unsigned short)(x >> 16);
}

__device__ __forceinline__ unsigned pack2(float a, float b) {
  float2 t; t.x = a; t.y = b;
  union { __hip_bfloat162 h; unsigned u; } cv;
  cv.h = __float22bfloat162_rn(t);
  return cv.u;
}

__device__ __forceinline__ float fexp2(float x) {
  float r; asm("v_exp_f32 %0, %1" : "=v"(r) : "v"(x)); return r;
}

// v_permlane32_swap_b32 vdst, vsrc — verified this session: vdst.row1 <-> vsrc.row0
#define PLSWAP(a,b) asm volatile("v_permlane32_swap_b32 %0, %1" : "+v"(a), "+v"(b))

__device__ __forceinline__ void gld_lds16(const void* g, void* l) {
  __builtin_amdgcn_global_load_lds(
      (const __attribute__((address_space(1))) void*)g,
      (__attribute__((address_space(3))) void*)l,
      16, 0, 0);
}

// Counted waits (sched_barrier fences per guide rule #18)
__device__ __forceinline__ void wait_vm2_barrier() {
  __builtin_amdgcn_sched_barrier(0);
  asm volatile("s_waitcnt vmcnt(2)" ::: "memory");
  __builtin_amdgcn_s_barrier();
  __builtin_amdgcn_sched_barrier(0);
}
__device__ __forceinline__ void wait_vm0_barrier() {
  __builtin_amdgcn_sched_barrier(0);
  asm volatile("s_waitcnt vmcnt(0)" ::: "memory");
  __builtin_amdgcn_s_barrier();
  __builtin_amdgcn_sched_barrier(0);
}
__device__ __forceinline__ void wait_lgkm_barrier() {   // reads retired; vmcnt NOT drained
  __builtin_amdgcn_sched_barrier(0);
  asm volatile("s_waitcnt lgkmcnt(0)" ::: "memory");
  __builtin_amdgcn_s_barrier();
  __builtin_amdgcn_sched_barrier(0);
}
__device__ __forceinline__ void phase_barrier() {       // pacing only; fenced defensively
  __builtin_amdgcn_sched_barrier(0);
  __builtin_amdgcn_s_barrier();
  __builtin_amdgcn_sched_barrier(0);
}

// All fp32->bf16 converts in one launch (unchanged control).
__global__ __launch_bounds__(256) void cvtall_kernel(
    const float* __restrict__ x,  unsigned short* __restrict__ xb,
    const float* __restrict__ w0, const float* __restrict__ w1,
    const float* __restrict__ w2, const float* __restrict__ w3,
    unsigned short* __restrict__ o0, unsigned short* __restrict__ o1,
    unsigned short* __restrict__ o2, unsigned short* __restrict__ o3) {
  int bid = blockIdx.x, tid = threadIdx.x;
  const float* in; unsigned short* out; int n4, i0, stride;
  if (bid < 2048) {
    in = x; out = xb; n4 = 4194304; i0 = bid * 256 + tid; stride = 2048 * 256;
  } else {
    int t = (bid - 2048) >> 7;
    switch (t) {
      case 0: in = w0; out = o0; break;
      case 1: in = w1; out = o1; break;
      case 2: in = w2; out = o2; break;
      default: in = w3; out = o3; break;
    }
    n4 = 262144; i0 = ((bid - 2048) & 127) * 256 + tid; stride = 128 * 256;
  }
  for (int i = i0; i < n4; i += stride) {
    float4 v = ((const float4*)in)[i];
    ushort4 o;
    o.x = f2bf(v.x); o.y = f2bf(v.y); o.z = f2bf(v.z); o.w = f2bf(v.w);
    ((ushort4*)out)[i] = o;
  }
}

// ===== 256(M)x128(N)-tile GEMM, BK=64, 4-phase K-step, counted vmcnt(2) =====
// 512 threads = 8 waves (4M x 2N); per-wave output 64x64 = acc[4][4] (64 VGPRs).
// LDS: A [2][256][64] = 64 KB, B [2][128][64] = 32 KB. Chunk-XOR involution (proven
// r6+): LDS[row][j] holds global chunk j^(row&7); reads apply the same XOR.
// 6 loads/thread/tile. Ledger: prologue 6; P0 +2 -> vmcnt(2) [6 oldest = tile kt
// landed]; P1 +2; P2 +1; P3 +1. Last tile: vmcnt(0). End-of-step lgkmcnt(0)+barrier
// guards buffer reuse; prefetch survives it (vmcnt != lgkmcnt).
// MODE: 0 fp32 [M][1024]; 1 Q bf16 (xQSC); 4 fused K|V (n<1024 K, else V^T at +VT_OFF)
template<int MODE, int ROWMUL>
__device__ __forceinline__ void gemm_body256(
    unsigned short* __restrict__ lA, unsigned short* __restrict__ lB,
    const unsigned short* __restrict__ A,
    const unsigned short* __restrict__ W,
    const float* __restrict__ biasA,
    const float* __restrict__ biasB,
    void* __restrict__ outp,
    int NB, int bid, int nwg)
{
  constexpr int K = 1024;
  int vid = (bid & 7) * (nwg >> 3) + (bid >> 3);   // bijective XCD swizzle (nwg%8==0)
  int bm = vid / NB, bn = vid % NB;

  int tid = threadIdx.x;
  int w = tid >> 6, l = tid & 63;
  int wm = w >> 1, wn = w & 1;        // 4M x 2N wave grid
  int fr = l & 15, fk = l >> 4;

  // staging: per region (64 rows), wave w covers rows w*8..w*8+7; lane l ->
  // row w*8+(l>>3), LDS chunk l&7, source chunk pre-swizzled (l&7)^(l>>3) = (l&7)^(row&7)
  int srow = w * 8 + (l >> 3);
  int pcs = ((l & 7) ^ (l >> 3)) * 8;
  const unsigned short* gA = A + (size_t)ROWMUL * ((size_t)(bm * 256 + srow) * K) + pcs;
  const unsigned short* gB = W + (size_t)(bn * 128 + srow) * K + pcs;
  int ldst = w * 512;                 // ushorts within a region

#define ST_A(B_, KT, I) gld_lds16(gA + (size_t)ROWMUL * 64 * (I) * K + (KT) * 64, \
                                  &lA[(B_) * 16384 + (I) * 4096 + ldst])
#define ST_B(B_, KT, I) gld_lds16(gB + (size_t)64 * (I) * K + (KT) * 64, \
                                  &lB[(B_) * 8192 + (I) * 4096 + ldst])

  f32x4 acc[4][4];
  #pragma unroll
  for (int i = 0; i < 4; ++i)
    #pragma unroll
    for (int j = 0; j < 4; ++j) acc[i][j] = (f32x4){0.f, 0.f, 0.f, 0.f};

  int rxor = fr & 7;                  // read-side XOR (row&7 == fr&7 for frag rows)

  // prologue: tile 0 -> buf 0 (6 loads/thread)
  ST_A(0, 0, 0); ST_A(0, 0, 1); ST_A(0, 0, 2); ST_A(0, 0, 3);
  ST_B(0, 0, 0); ST_B(0, 0, 1);

  for (int kt = 0; kt < 16; ++kt) {
    int b = kt & 1;
    int abA = b * 16384, abB = b * 8192;
    bool pre = (kt + 1 < 16);

#define PHASE(MI)                                                               \
    {                                                                           \
      short8 af[2];                                                             \
      _Pragma("unroll")                                                         \
      for (int kh = 0; kh < 2; ++kh)                                            \
        af[kh] = *(const short8*)&lA[abA + (wm * 64 + (MI) * 16 + fr) * 64      \
                                     + (((kh * 4 + fk) ^ rxor) * 8)];           \
      __builtin_amdgcn_s_setprio(1);                                            \
      _Pragma("unroll")                                                         \
      for (int nj = 0; nj < 4; ++nj)                                            \
        _Pragma("unroll")                                                       \
        for (int kh = 0; kh < 2; ++kh)                                          \
          acc[MI][nj] = MFMA16(af[kh], bfr[nj][kh], acc[MI][nj]);               \
      __builtin_amdgcn_s_setprio(0);                                            \
    }

    // ---- P0: issue 2 next-tile A, counted wait, read B-frags, mi=0 ----
    if (pre) { ST_A(b ^ 1, kt + 1, 0); ST_A(b ^ 1, kt + 1, 1); }
    if (pre) wait_vm2_barrier(); else wait_vm0_barrier();
    short8 bfr[4][2];
    #pragma unroll
    for (int nj = 0; nj < 4; ++nj)
      #pragma unroll
      for (int kh = 0; kh < 2; ++kh)
        bfr[nj][kh] = *(const short8*)&lB[abB + (wn * 64 + nj * 16 + fr) * 64
                                         + (((kh * 4 + fk) ^ rxor) * 8)];
    PHASE(0);
    phase_barrier();
    // ---- P1 ----
    if (pre) { ST_A(b ^ 1, kt + 1, 2); ST_A(b ^ 1, kt + 1, 3); }
    PHASE(1);
    phase_barrier();
    // ---- P2 ----
    if (pre) { ST_B(b ^ 1, kt + 1, 0); }
    PHASE(2);
    phase_barrier();
    // ---- P3 ----
    if (pre) { ST_B(b ^ 1, kt + 1, 1); }
    PHASE(3);
    wait_lgkm_barrier();   // reads of buf b retired everywhere; b may be overwritten next
#undef PHASE
  }
#undef ST_A
#undef ST_B

  float bv[4];
  #pragma unroll
  for (int nj = 0; nj < 4; ++nj) {
    int n = bn * 128 + wn * 64 + nj * 16 + fr;
    bv[nj] = (MODE == 4) ? (n < 1024 ? biasA[n] : biasB[n - 1024]) : biasA[n];
  }

  #pragma unroll
  for (int mi = 0; mi < 4; ++mi) {
    #pragma unroll
    for (int nj = 0; nj < 4; ++nj) {
      #pragma unroll
      for (int j = 0; j < 4; ++j) {
        int m = bm * 256 + wm * 64 + mi * 16 + fk * 4 + j;
        int n = bn * 128 + wn * 64 + nj * 16 + fr;
        float v = acc[mi][nj][j] + bv[nj];
        if (MODE == 0) {
          ((float*)outp)[(size_t)m * 1024 + n] = v;
        } else if (MODE == 1) {
          size_t idx = (size_t)((m >> 12) * 16 + (n >> 6)) * 262144
                     + (size_t)(m & 4095) * 64 + (n & 63);
          ((unsigned short*)outp)[idx] = f2bf(v * QSC);
        } else {                       // MODE 4: fused K|V
          if (n < 1024) {
            size_t idx = (size_t)((m >> 10) * 16 + (n >> 6)) * 65536
                       + (size_t)(m & 1023) * 64 + (n & 63);
            ((unsigned short*)outp)[idx] = f2bf(v);
          } else {
            int nn = n - 1024;
            size_t idx = (size_t)VT_OFF
                       + (size_t)((m >> 10) * 16 + (nn >> 6)) * 65536
                       + (size_t)(nn & 63) * 1024 + (m & 1023);
            ((unsigned short*)outp)[idx] = f2bf(v);
          }
        }
      }
    }
  }
}

// Q projection (blocks 0-511: 64 Mblk x 8 Nblk) and fused K/V projection
// (blocks 512-767: 16 Mblk x 16 Nblk = 256 blocks — M = B*S_k = 4096 rows).
__global__ __launch_bounds__(512) void proj_fused_kernel(
    const unsigned short* __restrict__ xb,
    const unsigned short* __restrict__ wqb,
    const unsigned short* __restrict__ wkb,
    const float* __restrict__ bq,
    const float* __restrict__ bk,
    const float* __restrict__ bv,
    unsigned short* __restrict__ qb,
    unsigned short* __restrict__ kb)
{
  __shared__ unsigned short lA[2 * 16384];   // 64 KB
  __shared__ unsigned short lB[2 * 8192];    // 32 KB
  int bid = blockIdx.x;
  if (bid < 512) {
    gemm_body256<1, 1>(lA, lB, xb, wqb, bq, bq, qb, 8, bid, 512);
  } else {
    gemm_body256<4, 4>(lA, lB, xb, wkb, bk, bv, kb, 16, bid - 512, 256);
  }
}

// O projection -> fp32 out (64 Mblk x 8 Nblk = 512 blocks)
__global__ __launch_bounds__(512) void oproj_kernel(
    const unsigned short* __restrict__ ab,
    const unsigned short* __restrict__ wob,
    const float* __restrict__ bo,
    float* __restrict__ out)
{
  __shared__ unsigned short lA[2 * 16384];
  __shared__ unsigned short lB[2 * 8192];
  gemm_body256<0, 1>(lA, lB, ab, wob, bo, bo, out, 8, blockIdx.x, 512);
}

// Flash attention (UNCHANGED control — passing rounds 11-14).
__global__ __launch_bounds__(512) void attn_kernel(
    const unsigned short* __restrict__ Q,
    const unsigned short* __restrict__ Ks,
    const unsigned short* __restrict__ Vt,
    unsigned short* __restrict__ O)
{
  __shared__ unsigned short lds[16384];     // 32 KB: K 2-buf | V 2-buf
  unsigned short* lsK = lds;
  unsigned short* lsV = lds + 8192;

  int bid = blockIdx.x;
  int vid = (bid & 7) * 128 + (bid >> 3);
  int bh = vid >> 4;
  int qt = vid & 15;
  int tid = threadIdx.x;
  int w = tid >> 6, l = tid & 63;
  int l31 = l & 31, hi = l >> 5;
  int q0 = qt * 256 + w * 32;

  short8 qf[4];
  {
    const unsigned short* qp = Q + ((size_t)bh * 4096 + q0 + l31) * 64 + hi * 8;
    #pragma unroll
    for (int s = 0; s < 4; ++s) qf[s] = *(const short8*)(qp + s * 16);
  }

  const unsigned short* Kbh = Ks + (size_t)bh * 65536;
  const unsigned short* Vbh = Vt + (size_t)bh * 65536;

  int r = w * 8 + (l >> 3);
  int c0 = ((l & 7) ^ (l >> 3)) * 8;
  int dst = w * 512;

#define STAGE(BUF, KC)                                                          \
  {                                                                             \
    const unsigned short* Kb = Kbh + (KC) * 4096;                               \
    const unsigned short* Vb = Vbh + (KC) * 64;                                 \
    gld_lds16(Kb + r * 64 + c0, &lsK[(BUF) * 4096 + dst]);                      \
    gld_lds16(Vb + (size_t)r * 1024 + c0, &lsV[(BUF) * 4096 + dst]);            \
  }

  float lrun = 0.f;
  f32x16 oa0, oa1;
  #pragma unroll
  for (int rr = 0; rr < 16; ++rr) { oa0[rr] = 0.f; oa1[rr] = 0.f; }

  STAGE(0, 0);
  __syncthreads();

  int rb0 = l31 * 64, rb1 = rb0 + 2048;
  int rsw = l31 & 7;

  for (int kc = 0; kc < 16; ++kc) {
    int b = kc & 1;
    if (kc + 1 < 16) STAGE(b ^ 1, kc + 1);

    const unsigned short* Kl = &lsK[b * 4096];
    const unsigned short* Vl = &lsV[b * 4096];

    f32x16 s0, s1;
    #pragma unroll
    for (int rr = 0; rr < 16; ++rr) { s0[rr] = 0.f; s1[rr] = 0.f; }
    __builtin_amdgcn_s_setprio(1);
    #pragma unroll
    for (int s = 0; s < 4; ++s) {
      int co = ((hi + 2 * s) ^ rsw) * 8;
      short8 kf0 = *(const short8*)&Kl[rb0 + co];
      short8 kf1 = *(const short8*)&Kl[rb1 + co];
      s0 = MFMA32(kf0, qf[s], s0);
      s1 = MFMA32(kf1, qf[s], s1);
    }
    __builtin_amdgcn_s_setprio(0);

    unsigned pk0[8], pk1[8];
    float sm0 = 0.f, sm1 = 0.f, sm2 = 0.f, sm3 = 0.f;
    #pragma unroll
    for (int i = 0; i < 4; ++i) {
      float a = fexp2(s0[2*i]), bb = fexp2(s0[2*i+1]);
      sm0 += a + bb; pk0[i] = pack2(a, bb);
    }
    #pragma unroll
    for (int i = 4; i < 8; ++i) {
      float a = fexp2(s0[2*i]), bb = fexp2(s0[2*i+1]);
      sm1 += a + bb; pk0[i] = pack2(a, bb);
    }
    #pragma unroll
    for (int i = 0; i < 4; ++i) {
      float a = fexp2(s1[2*i]), bb = fexp2(s1[2*i+1]);
      sm2 += a + bb; pk1[i] = pack2(a, bb);
    }
    #pragma unroll
    for (int i = 4; i < 8; ++i) {
      float a = fexp2(s1[2*i]), bb = fexp2(s1[2*i+1]);
      sm3 += a + bb; pk1[i] = pack2(a, bb);
    }
    lrun += (sm0 + sm1) + (sm2 + sm3);

    short8 pf[4];
    #pragma unroll
    for (int half = 0; half < 2; ++half) {
      #pragma unroll
      for (int sl = 0; sl < 2; ++sl) {
        unsigned a0 = half ? pk1[sl*4+0] : pk0[sl*4+0];
        unsigned a1 = half ? pk1[sl*4+1] : pk0[sl*4+1];
        unsigned b0 = half ? pk1[sl*4+2] : pk0[sl*4+2];
        unsigned b1 = half ? pk1[sl*4+3] : pk0[sl*4+3];
        unsigned t0 = a0; PLSWAP(t0, b0);
        unsigned t1 = a1; PLSWAP(t1, b1);
        union { unsigned u[4]; short8 s8; } u;
        u.u[0] = t0;
        u.u[1] = t1;
        u.u[2] = b0;
        u.u[3] = b1;
        pf[half * 2 + sl] = u.s8;
      }
    }

    __builtin_amdgcn_s_setprio(1);
    #pragma unroll
    for (int s = 0; s < 4; ++s) {
      int co = ((hi + 2 * s) ^ rsw) * 8;
      short8 vf0 = *(const short8*)&Vl[rb0 + co];
      short8 vf1 = *(const short8*)&Vl[rb1 + co];
      oa0 = MFMA32(vf0, pf[s], oa0);
      oa1 = MFMA32(vf1, pf[s], oa1);
    }
    __builtin_amdgcn_s_setprio(0);

    __syncthreads();
  }
#undef STAGE

  lrun += __shfl_xor(lrun, 32);
  float inv = 1.0f / lrun;

  unsigned short* ob = lds + w * 2048;
  #pragma unroll
  for (int dblk = 0; dblk < 2; ++dblk) {
    #pragma unroll
    for (int rr = 0; rr < 16; ++rr) {
      float v = (dblk ? oa1[rr] : oa0[rr]) * inv;
      int d = dblk * 32 + (rr & 3) + 8 * (rr >> 2) + 4 * hi;
      ob[l31 * 64 + (d ^ ((l31 & 7) << 3))] = f2bf(v);
    }
  }
  int b = bh >> 4, h = bh & 15;
  #pragma unroll
  for (int pass = 0; pass < 8; ++pass) {
    int qq = pass * 4 + (l >> 4);
    int cc = (l & 15) * 4;
    ushort4 vv = *(const ushort4*)&ob[qq * 64 + (cc ^ ((qq & 7) << 3))];
    *(ushort4*)&O[((size_t)b * 4096 + q0 + qq) * 1024 + h * 64 + cc] = vv;
  }
}

extern "C" void kernel_launch(void* const* d_in, const int* in_sizes, int n_in,
                              void* d_out, int out_size, void* d_ws, size_t ws_size,
                              hipStream_t stream) {
  const float* x  = (const float*)d_in[0];
  const float* Wq = (const float*)d_in[1];
  const float* bq = (const float*)d_in[2];
  const float* Wk = (const float*)d_in[3];
  const float* bk = (const float*)d_in[4];
  const float* Wv = (const float*)d_in[5];
  const float* bv = (const float*)d_in[6];
  const float* Wo = (const float*)d_in[7];
  const float* bo = (const float*)d_in[8];
  float* out = (float*)d_out;

  unsigned short* ws  = (unsigned short*)d_ws;
  unsigned short* xb  = ws;                    // x bf16 [16384][1024]
  unsigned short* wqb = xb  + 16777216;
  unsigned short* wkb = wqb + 1048576;         // wkb/wvb contiguous -> fused KV GEMM
  unsigned short* wvb = wkb + 1048576;
  unsigned short* wob = wvb + 1048576;
  unsigned short* qb  = wob + 1048576;         // Q [64][4096][64] (pre-scaled)
  unsigned short* kb  = qb  + 16777216;        // K [64][1024][64]
  unsigned short* vtb = kb  + 4194304;         // V^T [64][64][1024]  (= kb + VT_OFF)
  unsigned short* ab  = vtb + 4194304;         // attn out [16384][1024]

  cvtall_kernel<<<2560, 256, 0, stream>>>(x, xb, Wq, Wk, Wv, Wo, wqb, wkb, wvb, wob);
  proj_fused_kernel<<<768, 512, 0, stream>>>(xb, wqb, wkb, bq, bk, bv, qb, kb);
  attn_kernel<<<1024, 512, 0, stream>>>(qb, kb, vtb, ab);
  oproj_kernel<<<512, 512, 0, stream>>>(ab, wob, bo, out);
}

// Round 18
// 222.636 us; speedup vs baseline: 1.3318x; 1.3318x over previous
//
#include <hip/hip_runtime.h>
#include <hip/hip_bf16.h>
#include <stdint.h>

// B=4, S=4096, DIMS=1024, HEAD=16, HD=64, skip=4 (S_k=1024)
// FINAL (round-14 configuration, best passing: 222.9 us):
// cvtall(x,W*) -> proj_fused (Q proj | K/V proj, 128x128 tile, BK=64, stage-ahead dbuf
// with counted vmcnt(8) + raw barriers) -> flash attn (8-wave blocks, LDS-staged K/V,
// 32x32 swapped QK^T, no-max exp2 softmax, cvt_pk + permlane32_swap P repack) ->
// oproj (same counted-vmcnt GEMM loop)

using short8 = short __attribute__((ext_vector_type(8)));
using f32x4  = float __attribute__((ext_vector_type(4)));
using f32x16 = float __attribute__((ext_vector_type(16)));

#define MFMA16(A,B,C) __builtin_amdgcn_mfma_f32_16x16x32_bf16((A),(B),(C),0,0,0)
#define MFMA32(A,B,C) __builtin_amdgcn_mfma_f32_32x32x16_bf16((A),(B),(C),0,0,0)

// scale * log2(e), folded into Q projection epilogue
#define QSC 0.0450842200277800f

// V^T buffer offset (in ushorts) relative to the K buffer, for the fused K|V GEMM
#define VT_OFF 4194304

__device__ __forceinline__ unsigned short f2bf(float f) {
  unsigned int x = __float_as_uint(f);
  x += 0x7fffu + ((x >> 16) & 1u);   // RNE
  return (unsigned short)(x >> 16);
}

// bf16 pair pack via HIP intrinsic (compiler emits v_cvt_pk_bf16_f32): a->lo, b->hi
__device__ __forceinline__ unsigned pack2(float a, float b) {
  float2 t; t.x = a; t.y = b;
  union { __hip_bfloat162 h; unsigned u; } cv;
  cv.h = __float22bfloat162_rn(t);
  return cv.u;
}

__device__ __forceinline__ float fexp2(float x) {
  float r; asm("v_exp_f32 %0, %1" : "=v"(r) : "v"(x)); return r;
}

// v_permlane32_swap_b32 vdst, vsrc — verified this session: vdst.row1 <-> vsrc.row0
#define PLSWAP(a,b) asm volatile("v_permlane32_swap_b32 %0, %1" : "+v"(a), "+v"(b))

__device__ __forceinline__ void gld_lds16(const void* g, void* l) {
  __builtin_amdgcn_global_load_lds(
      (const __attribute__((address_space(1))) void*)g,
      (__attribute__((address_space(3))) void*)l,
      16, 0, 0);
}

// Counted-vmcnt barrier: my tile-kt loads (8 oldest of 16 outstanding) have landed;
// then block-wide barrier => ALL waves' tile-kt data is in LDS. Next-tile loads stay
// in flight. sched_barrier(0) fences per guide rule #18.
__device__ __forceinline__ void wait_vm8_barrier() {
  __builtin_amdgcn_sched_barrier(0);
  asm volatile("s_waitcnt vmcnt(8)" ::: "memory");
  __builtin_amdgcn_s_barrier();
  __builtin_amdgcn_sched_barrier(0);
}
__device__ __forceinline__ void wait_vm0_barrier() {
  __builtin_amdgcn_sched_barrier(0);
  asm volatile("s_waitcnt vmcnt(0)" ::: "memory");
  __builtin_amdgcn_s_barrier();
  __builtin_amdgcn_sched_barrier(0);
}
// Reads-retired barrier: ds_read results are in VGPRs (lgkmcnt 0) for every wave =>
// safe for the next iteration to overwrite this LDS buffer. Does NOT drain vmcnt.
__device__ __forceinline__ void wait_lgkm_barrier() {
  __builtin_amdgcn_sched_barrier(0);
  asm volatile("s_waitcnt lgkmcnt(0)" ::: "memory");
  __builtin_amdgcn_s_barrier();
  __builtin_amdgcn_sched_barrier(0);
}

// All fp32->bf16 converts in one launch: blocks 0-2047 convert x (grid-stride),
// blocks 2048-2559 convert the four 1024x1024 weights (128 blocks each).
__global__ __launch_bounds__(256) void cvtall_kernel(
    const float* __restrict__ x,  unsigned short* __restrict__ xb,
    const float* __restrict__ w0, const float* __restrict__ w1,
    const float* __restrict__ w2, const float* __restrict__ w3,
    unsigned short* __restrict__ o0, unsigned short* __restrict__ o1,
    unsigned short* __restrict__ o2, unsigned short* __restrict__ o3) {
  int bid = blockIdx.x, tid = threadIdx.x;
  const float* in; unsigned short* out; int n4, i0, stride;
  if (bid < 2048) {
    in = x; out = xb; n4 = 4194304; i0 = bid * 256 + tid; stride = 2048 * 256;
  } else {
    int t = (bid - 2048) >> 7;
    switch (t) {
      case 0: in = w0; out = o0; break;
      case 1: in = w1; out = o1; break;
      case 2: in = w2; out = o2; break;
      default: in = w3; out = o3; break;
    }
    n4 = 262144; i0 = ((bid - 2048) & 127) * 256 + tid; stride = 128 * 256;
  }
  for (int i = i0; i < n4; i += stride) {
    float4 v = ((const float4*)in)[i];
    ushort4 o;
    o.x = f2bf(v.x); o.y = f2bf(v.y); o.z = f2bf(v.z); o.w = f2bf(v.w);
    ((ushort4*)out)[i] = o;
  }
}

// C = A * W^T + bias. 128x128 tile, 4 waves, BK=64, stage-ahead double buffer with
// COUNTED vmcnt(8): next-tile global_load_lds remain in flight through compute.
// Per K-step: STAGE(next) -> vmcnt(8)+barrier -> ds_read+MFMA -> lgkmcnt(0)+barrier.
// MODE: 0 fp32 [M][1024]; 1 Q bf16 [b,h,s,64] (pre-scaled by QSC);
//       4 fused K|V (N=2048: n<1024 -> K layout w/ biasA, n>=1024 -> V^T at outp+VT_OFF)
template<int MODE, int ROWMUL>
__device__ __forceinline__ void gemm_body(
    unsigned short* __restrict__ lA, unsigned short* __restrict__ lB,
    const unsigned short* __restrict__ A,
    const unsigned short* __restrict__ W,
    const float* __restrict__ biasA,
    const float* __restrict__ biasB,
    void* __restrict__ outp,
    int NB, int bid, int nwg)
{
  constexpr int K = 1024;
  int vid = (bid & 7) * (nwg >> 3) + (bid >> 3);   // bijective XCD swizzle (nwg%8==0)
  int bm = vid / NB, bn = vid % NB;

  int tid = threadIdx.x;
  int w = tid >> 6, l = tid & 63;
  int wm = w >> 1, wn = w & 1;
  int fr = l & 15, fk = l >> 4;

  int sr = w * 16 + (l >> 2);
  int sc = ((l & 3) ^ ((l >> 3) & 3)) * 8;
  const unsigned short* ga0 = A + (size_t)ROWMUL * (size_t)(bm * 128 + sr) * K + sc;
  const unsigned short* ga1 = A + (size_t)ROWMUL * (size_t)(bm * 128 + 64 + sr) * K + sc;
  const unsigned short* gb0 = W + (size_t)(bn * 128 + sr) * K + sc;
  const unsigned short* gb1 = W + (size_t)(bn * 128 + 64 + sr) * K + sc;
  int la0 = (w * 16) * 32;
  int la1 = (64 + w * 16) * 32;

  int physk = (fk ^ ((fr >> 1) & 3)) * 8;

  f32x4 acc[4][4];
  #pragma unroll
  for (int i = 0; i < 4; ++i)
    #pragma unroll
    for (int j = 0; j < 4; ++j) acc[i][j] = (f32x4){0.f, 0.f, 0.f, 0.f};

  // stage tile kt into buffer BUF (8 async 16B loads/thread; both 32-col halves)
#define GSTAGE(BUF, KT)                                                         \
  {                                                                             \
    int o = (BUF) * 8192;                                                       \
    gld_lds16(ga0 + (KT) * 64,      &lA[o + la0]);                              \
    gld_lds16(ga0 + (KT) * 64 + 32, &lA[o + la0 + 4096]);                       \
    gld_lds16(ga1 + (KT) * 64,      &lA[o + la1]);                              \
    gld_lds16(ga1 + (KT) * 64 + 32, &lA[o + la1 + 4096]);                       \
    gld_lds16(gb0 + (KT) * 64,      &lB[o + la0]);                              \
    gld_lds16(gb0 + (KT) * 64 + 32, &lB[o + la0 + 4096]);                       \
    gld_lds16(gb1 + (KT) * 64,      &lB[o + la1]);                              \
    gld_lds16(gb1 + (KT) * 64 + 32, &lB[o + la1 + 4096]);                       \
  }

  GSTAGE(0, 0);

  for (int kt = 0; kt < K / 64; ++kt) {
    int b = kt & 1;
    if (kt + 1 < K / 64) {
      GSTAGE(b ^ 1, kt + 1);   // +8 loads -> 16 outstanding; oldest 8 = tile kt
      wait_vm8_barrier();      // tile kt landed everywhere; kt+1 stays in flight
    } else {
      wait_vm0_barrier();      // last tile: only its 8 outstanding
    }

    #pragma unroll
    for (int kh = 0; kh < 2; ++kh) {
      int base = b * 8192 + kh * 4096;
      short8 af[4], bf[4];
      #pragma unroll
      for (int mi = 0; mi < 4; ++mi)
        af[mi] = *(const short8*)&lA[base + (wm * 64 + mi * 16 + fr) * 32 + physk];
      #pragma unroll
      for (int nj = 0; nj < 4; ++nj)
        bf[nj] = *(const short8*)&lB[base + (wn * 64 + nj * 16 + fr) * 32 + physk];
      __builtin_amdgcn_s_setprio(1);
      #pragma unroll
      for (int mi = 0; mi < 4; ++mi)
        #pragma unroll
        for (int nj = 0; nj < 4; ++nj)
          acc[mi][nj] = MFMA16(af[mi], bf[nj], acc[mi][nj]);
      __builtin_amdgcn_s_setprio(0);
    }

    wait_lgkm_barrier();       // reads retired; next iter may overwrite buf b
  }
#undef GSTAGE

  float bv[4];
  #pragma unroll
  for (int nj = 0; nj < 4; ++nj) {
    int n = bn * 128 + wn * 64 + nj * 16 + fr;
    bv[nj] = (MODE == 4) ? (n < 1024 ? biasA[n] : biasB[n - 1024]) : biasA[n];
  }

  #pragma unroll
  for (int mi = 0; mi < 4; ++mi) {
    #pragma unroll
    for (int nj = 0; nj < 4; ++nj) {
      #pragma unroll
      for (int j = 0; j < 4; ++j) {
        int m = bm * 128 + wm * 64 + mi * 16 + fk * 4 + j;
        int n = bn * 128 + wn * 64 + nj * 16 + fr;
        float v = acc[mi][nj][j] + bv[nj];
        if (MODE == 0) {
          ((float*)outp)[(size_t)m * 1024 + n] = v;
        } else if (MODE == 1) {
          size_t idx = (size_t)((m >> 12) * 16 + (n >> 6)) * 262144
                     + (size_t)(m & 4095) * 64 + (n & 63);
          ((unsigned short*)outp)[idx] = f2bf(v * QSC);
        } else {                       // MODE 4: fused K|V
          if (n < 1024) {              // K: [b][h][s'][hd] at outp
            size_t idx = (size_t)((m >> 10) * 16 + (n >> 6)) * 65536
                       + (size_t)(m & 1023) * 64 + (n & 63);
            ((unsigned short*)outp)[idx] = f2bf(v);
          } else {                     // V^T: [b][h][hd][s'] at outp + VT_OFF
            int nn = n - 1024;
            size_t idx = (size_t)VT_OFF
                       + (size_t)((m >> 10) * 16 + (nn >> 6)) * 65536
                       + (size_t)(nn & 63) * 1024 + (m & 1023);
            ((unsigned short*)outp)[idx] = f2bf(v);
          }
        }
      }
    }
  }
}

// Q projection (blocks 0-1023) and fused K/V projection (blocks 1024-1535) in one launch.
__global__ __launch_bounds__(256) void proj_fused_kernel(
    const unsigned short* __restrict__ xb,
    const unsigned short* __restrict__ wqb,
    const unsigned short* __restrict__ wkb,
    const float* __restrict__ bq,
    const float* __restrict__ bk,
    const float* __restrict__ bv,
    unsigned short* __restrict__ qb,
    unsigned short* __restrict__ kb)
{
  __shared__ unsigned short lA[2 * 8192];   // 2 bufs x 16 KB
  __shared__ unsigned short lB[2 * 8192];
  int bid = blockIdx.x;
  if (bid < 1024) {
    gemm_body<1, 1>(lA, lB, xb, wqb, bq, bq, qb, 8, bid, 1024);
  } else {
    gemm_body<4, 4>(lA, lB, xb, wkb, bk, bv, kb, 16, bid - 1024, 512);
  }
}

// O projection -> fp32 out
__global__ __launch_bounds__(256) void oproj_kernel(
    const unsigned short* __restrict__ ab,
    const unsigned short* __restrict__ wob,
    const float* __restrict__ bo,
    float* __restrict__ out)
{
  __shared__ unsigned short lA[2 * 8192];
  __shared__ unsigned short lB[2 * 8192];
  gemm_body<0, 1>(lA, lB, ab, wob, bo, bo, out, 8, blockIdx.x, 1024);
}

// Flash attention (UNCHANGED — passing rounds 11-14, 88 us, 90% issue-busy):
// 8 waves/block, wave = 32 q-rows, 64-key chunks, 32x32x16 MFMA, LDS-staged K/V
// (chunk-XOR preswizzle, dbuf), swapped QK^T, no-max exp2 softmax, cvt_pk +
// permlane32_swap P repack, PV = Vt x P.
__global__ __launch_bounds__(512) void attn_kernel(
    const unsigned short* __restrict__ Q,
    const unsigned short* __restrict__ Ks,
    const unsigned short* __restrict__ Vt,
    unsigned short* __restrict__ O)
{
  __shared__ unsigned short lds[16384];     // 32 KB: [0..8191]=K 2-buf, [8192..]=V 2-buf
  unsigned short* lsK = lds;
  unsigned short* lsV = lds + 8192;

  int bid = blockIdx.x;
  int vid = (bid & 7) * 128 + (bid >> 3);   // bijective XCD swizzle (1024 blocks)
  int bh = vid >> 4;                         // 8 bh per XCD chunk -> K/V L2-resident
  int qt = vid & 15;
  int tid = threadIdx.x;
  int w = tid >> 6, l = tid & 63;
  int l31 = l & 31, hi = l >> 5;
  int q0 = qt * 256 + w * 32;

  short8 qf[4];
  {
    const unsigned short* qp = Q + ((size_t)bh * 4096 + q0 + l31) * 64 + hi * 8;
    #pragma unroll
    for (int s = 0; s < 4; ++s) qf[s] = *(const short8*)(qp + s * 16);
  }

  const unsigned short* Kbh = Ks + (size_t)bh * 65536;
  const unsigned short* Vbh = Vt + (size_t)bh * 65536;

  int r = w * 8 + (l >> 3);
  int c0 = ((l & 7) ^ (l >> 3)) * 8;        // ushort offset
  int dst = w * 512;                         // ushort offset within buffer

#define STAGE(BUF, KC)                                                          \
  {                                                                             \
    const unsigned short* Kb = Kbh + (KC) * 4096;                               \
    const unsigned short* Vb = Vbh + (KC) * 64;                                 \
    gld_lds16(Kb + r * 64 + c0, &lsK[(BUF) * 4096 + dst]);                      \
    gld_lds16(Vb + (size_t)r * 1024 + c0, &lsV[(BUF) * 4096 + dst]);            \
  }

  float lrun = 0.f;
  f32x16 oa0, oa1;
  #pragma unroll
  for (int rr = 0; rr < 16; ++rr) { oa0[rr] = 0.f; oa1[rr] = 0.f; }

  STAGE(0, 0);
  __syncthreads();

  int rb0 = l31 * 64, rb1 = rb0 + 2048;     // LDS row bases (ushorts): key/d = l31, l31+32
  int rsw = l31 & 7;                         // read-side XOR

  for (int kc = 0; kc < 16; ++kc) {
    int b = kc & 1;
    if (kc + 1 < 16) STAGE(b ^ 1, kc + 1);

    const unsigned short* Kl = &lsK[b * 4096];
    const unsigned short* Vl = &lsV[b * 4096];

    f32x16 s0, s1;
    #pragma unroll
    for (int rr = 0; rr < 16; ++rr) { s0[rr] = 0.f; s1[rr] = 0.f; }
    __builtin_amdgcn_s_setprio(1);
    #pragma unroll
    for (int s = 0; s < 4; ++s) {
      int co = ((hi + 2 * s) ^ rsw) * 8;
      short8 kf0 = *(const short8*)&Kl[rb0 + co];
      short8 kf1 = *(const short8*)&Kl[rb1 + co];
      s0 = MFMA32(kf0, qf[s], s0);   // S[key=(r&3)+8*(r>>2)+4*hi][q=l31]
      s1 = MFMA32(kf1, qf[s], s1);
    }
    __builtin_amdgcn_s_setprio(0);

    unsigned pk0[8], pk1[8];
    float sm0 = 0.f, sm1 = 0.f, sm2 = 0.f, sm3 = 0.f;
    #pragma unroll
    for (int i = 0; i < 4; ++i) {
      float a = fexp2(s0[2*i]), bb = fexp2(s0[2*i+1]);
      sm0 += a + bb; pk0[i] = pack2(a, bb);
    }
    #pragma unroll
    for (int i = 4; i < 8; ++i) {
      float a = fexp2(s0[2*i]), bb = fexp2(s0[2*i+1]);
      sm1 += a + bb; pk0[i] = pack2(a, bb);
    }
    #pragma unroll
    for (int i = 0; i < 4; ++i) {
      float a = fexp2(s1[2*i]), bb = fexp2(s1[2*i+1]);
      sm2 += a + bb; pk1[i] = pack2(a, bb);
    }
    #pragma unroll
    for (int i = 4; i < 8; ++i) {
      float a = fexp2(s1[2*i]), bb = fexp2(s1[2*i+1]);
      sm3 += a + bb; pk1[i] = pack2(a, bb);
    }
    lrun += (sm0 + sm1) + (sm2 + sm3);

    short8 pf[4];
    #pragma unroll
    for (int half = 0; half < 2; ++half) {
      #pragma unroll
      for (int sl = 0; sl < 2; ++sl) {
        unsigned a0 = half ? pk1[sl*4+0] : pk0[sl*4+0];
        unsigned a1 = half ? pk1[sl*4+1] : pk0[sl*4+1];
        unsigned b0 = half ? pk1[sl*4+2] : pk0[sl*4+2];
        unsigned b1 = half ? pk1[sl*4+3] : pk0[sl*4+3];
        unsigned t0 = a0; PLSWAP(t0, b0);
        unsigned t1 = a1; PLSWAP(t1, b1);
        union { unsigned u[4]; short8 s8; } u;
        u.u[0] = t0;   // keys 16sl+8hi+{0,1}
        u.u[1] = t1;   // keys 16sl+8hi+{2,3}
        u.u[2] = b0;   // keys 16sl+8hi+{4,5}
        u.u[3] = b1;   // keys 16sl+8hi+{6,7}
        pf[half * 2 + sl] = u.s8;
      }
    }

    __builtin_amdgcn_s_setprio(1);
    #pragma unroll
    for (int s = 0; s < 4; ++s) {
      int co = ((hi + 2 * s) ^ rsw) * 8;
      short8 vf0 = *(const short8*)&Vl[rb0 + co];
      short8 vf1 = *(const short8*)&Vl[rb1 + co];
      oa0 = MFMA32(vf0, pf[s], oa0);   // O^T[d=(r&3)+8*(r>>2)+4*hi][q=l31]
      oa1 = MFMA32(vf1, pf[s], oa1);
    }
    __builtin_amdgcn_s_setprio(0);

    __syncthreads();   // drains next-chunk staging loads; guards buffer reuse
  }
#undef STAGE

  lrun += __shfl_xor(lrun, 32);
  float inv = 1.0f / lrun;

  unsigned short* ob = lds + w * 2048;
  #pragma unroll
  for (int dblk = 0; dblk < 2; ++dblk) {
    #pragma unroll
    for (int rr = 0; rr < 16; ++rr) {
      float v = (dblk ? oa1[rr] : oa0[rr]) * inv;
      int d = dblk * 32 + (rr & 3) + 8 * (rr >> 2) + 4 * hi;
      ob[l31 * 64 + (d ^ ((l31 & 7) << 3))] = f2bf(v);
    }
  }
  int b = bh >> 4, h = bh & 15;
  #pragma unroll
  for (int pass = 0; pass < 8; ++pass) {
    int qq = pass * 4 + (l >> 4);
    int cc = (l & 15) * 4;
    ushort4 vv = *(const ushort4*)&ob[qq * 64 + (cc ^ ((qq & 7) << 3))];
    *(ushort4*)&O[((size_t)b * 4096 + q0 + qq) * 1024 + h * 64 + cc] = vv;
  }
}

extern "C" void kernel_launch(void* const* d_in, const int* in_sizes, int n_in,
                              void* d_out, int out_size, void* d_ws, size_t ws_size,
                              hipStream_t stream) {
  const float* x  = (const float*)d_in[0];
  const float* Wq = (const float*)d_in[1];
  const float* bq = (const float*)d_in[2];
  const float* Wk = (const float*)d_in[3];
  const float* bk = (const float*)d_in[4];
  const float* Wv = (const float*)d_in[5];
  const float* bv = (const float*)d_in[6];
  const float* Wo = (const float*)d_in[7];
  const float* bo = (const float*)d_in[8];
  float* out = (float*)d_out;

  unsigned short* ws  = (unsigned short*)d_ws;
  unsigned short* xb  = ws;                    // x bf16 [16384][1024]
  unsigned short* wqb = xb  + 16777216;
  unsigned short* wkb = wqb + 1048576;         // wkb/wvb contiguous -> fused KV GEMM
  unsigned short* wvb = wkb + 1048576;
  unsigned short* wob = wvb + 1048576;
  unsigned short* qb  = wob + 1048576;         // Q [64][4096][64] (pre-scaled)
  unsigned short* kb  = qb  + 16777216;        // K [64][1024][64]
  unsigned short* vtb = kb  + 4194304;         // V^T [64][64][1024]  (= kb + VT_OFF)
  unsigned short* ab  = vtb + 4194304;         // attn out [16384][1024]

  cvtall_kernel<<<2560, 256, 0, stream>>>(x, xb, Wq, Wk, Wv, Wo, wqb, wkb, wvb, wob);
  proj_fused_kernel<<<1536, 256, 0, stream>>>(xb, wqb, wkb, bq, bk, bv, qb, kb);
  attn_kernel<<<1024, 512, 0, stream>>>(qb, kb, vtb, ab);
  oproj_kernel<<<1024, 256, 0, stream>>>(ab, wob, bo, out);
}